// Round 2
// baseline (343.963 us; speedup 1.0000x reference)
//
#include <hip/hip_runtime.h>

typedef unsigned short u16;
typedef unsigned int u32;
typedef __attribute__((ext_vector_type(8))) __bf16 bf16x8;
typedef __attribute__((ext_vector_type(4))) float f32x4;
typedef __attribute__((ext_vector_type(16))) float f32x16;

#define EMBED 1024
#define NB 2
#define LQ 2048
#define HEADS 16
#define DH 64
// log2(e) / sqrt(64) -- folded into Q at projection time
#define QSCALE 0.18033688011112042f

__device__ __forceinline__ u16 f2bf(float f) {
  u32 u = __float_as_uint(f);
  u32 r = (u + 0x7FFFu + ((u >> 16) & 1u)) >> 16;  // RNE
  return (u16)r;
}

__device__ __forceinline__ void glds16(const void* g, void* l) {
  __builtin_amdgcn_global_load_lds((const __attribute__((address_space(1))) void*)g,
                                   (__attribute__((address_space(3))) void*)l, 16, 0, 0);
}

__device__ __forceinline__ f32x4 mfma16(bf16x8 a, bf16x8 b, f32x4 c) {
  return __builtin_amdgcn_mfma_f32_16x16x32_bf16(a, b, c, 0, 0, 0);
}
__device__ __forceinline__ f32x16 mfma32(bf16x8 a, bf16x8 b, f32x16 c) {
  return __builtin_amdgcn_mfma_f32_32x32x16_bf16(a, b, c, 0, 0, 0);
}

// v_permlane32_swap_b32: a[l>=32] <-> b[l-32]. Register-only exchange.
__device__ __forceinline__ void pl32(u32& a, u32& b) {
  asm("v_permlane32_swap_b32 %0, %1" : "+v"(a), "+v"(b));
}

// pack two floats to bf16 pair (truncating): low = a, high = b
__device__ __forceinline__ u32 packbf(float a, float b) {
  return __builtin_amdgcn_perm(__float_as_uint(b), __float_as_uint(a), 0x07060302u);
}

// ---------------- cast fp32 -> bf16 for activations + weights ----------------
__global__ __launch_bounds__(256) void cast_kernel(
    const float* __restrict__ q, const float* __restrict__ kv,
    const float* __restrict__ wq, const float* __restrict__ wk,
    const float* __restrict__ wv, const float* __restrict__ wo,
    u16* __restrict__ qb, u16* __restrict__ kvb, u16* __restrict__ wqb,
    u16* __restrict__ wkb, u16* __restrict__ wvb, u16* __restrict__ wob) {
  int bid = blockIdx.x;
  const float* src;
  u16* dst;
  long base;
  if (bid < 2048) {
    src = q; dst = qb; base = (long)bid * 2048;
  } else if (bid < 4096) {
    src = kv; dst = kvb; base = (long)(bid - 2048) * 2048;
  } else {
    int wsel = (bid - 4096) >> 9;
    int wb = (bid - 4096) & 511;
    if (wsel == 0) { src = wq; dst = wqb; }
    else if (wsel == 1) { src = wk; dst = wkb; }
    else if (wsel == 2) { src = wv; dst = wvb; }
    else { src = wo; dst = wob; }
    base = (long)wb * 2048;
  }
  long e = base + (long)threadIdx.x * 8;
  float4 f0 = *(const float4*)(src + e);
  float4 f1 = *(const float4*)(src + e + 4);
  uint4 o;
  o.x = (u32)f2bf(f0.x) | ((u32)f2bf(f0.y) << 16);
  o.y = (u32)f2bf(f0.z) | ((u32)f2bf(f0.w) << 16);
  o.z = (u32)f2bf(f1.x) | ((u32)f2bf(f1.y) << 16);
  o.w = (u32)f2bf(f1.z) | ((u32)f2bf(f1.w) << 16);
  *(uint4*)(dst + e) = o;
}

// ------------- GEMM: C = A @ W^T (+bias, mode-specific epilogue), BK=64 ------
// mode 0: Q -> [bh][L][64], scaled by QSCALE; 1: K -> same layout unscaled;
// mode 2: V -> [bh][64][L] (transposed, b64-packed stores);
// mode 3: fp32 out = acc + bias + resid (pre-LN x).
template <int IT>
__device__ __forceinline__ void gemm_core(
    u16* As, u16* Bs, const u16* __restrict__ A, const u16* __restrict__ W,
    const float* __restrict__ bias, const float* __restrict__ resid,
    void* __restrict__ outp, int mode, int bx, int by) {
  const int K = EMBED;
  const int TM = IT * 32;
  const int tid = threadIdx.x;
  const int lane = tid & 63;
  const int wv = tid >> 6;
  const int wm = wv >> 1, wn = wv & 1;
  const int l16 = lane & 15, quad = lane >> 4;
  const long tile_m = (long)bx * TM;
  const long tile_n = (long)by * 128;

  f32x4 z4 = {0.f, 0.f, 0.f, 0.f};
  f32x4 acc[IT][4];
#pragma unroll
  for (int i = 0; i < IT; i++)
#pragma unroll
    for (int j = 0; j < 4; j++) acc[i][j] = z4;

  for (int k0 = 0; k0 < K; k0 += 64) {
    // stage A: TM rows x 8 chunks(16B), XOR swizzle cc ^ (row&7)
#pragma unroll
    for (int it = 0; it < TM / 32; it++) {
      int lin = it * 256 + tid;
      int row = lin >> 3, cc = lin & 7;
      glds16(A + (tile_m + row) * K + k0 + ((cc ^ (row & 7)) << 3), As + lin * 8);
    }
#pragma unroll
    for (int it = 0; it < 4; it++) {
      int lin = it * 256 + tid;
      int row = lin >> 3, cc = lin & 7;
      glds16(W + (tile_n + row) * K + k0 + ((cc ^ (row & 7)) << 3), Bs + lin * 8);
    }
    __syncthreads();
    bf16x8 af[IT][2], bfr[4][2];
#pragma unroll
    for (int i = 0; i < IT; i++) {
      int row = wm * (IT * 16) + i * 16 + l16;
#pragma unroll
      for (int ki = 0; ki < 2; ki++)
        af[i][ki] = *(const bf16x8*)(As + row * 64 + (((ki * 4 + quad) ^ (row & 7)) << 3));
    }
#pragma unroll
    for (int j = 0; j < 4; j++) {
      int row = wn * 64 + j * 16 + l16;
#pragma unroll
      for (int ki = 0; ki < 2; ki++)
        bfr[j][ki] = *(const bf16x8*)(Bs + row * 64 + (((ki * 4 + quad) ^ (row & 7)) << 3));
    }
#pragma unroll
    for (int ki = 0; ki < 2; ki++)
#pragma unroll
      for (int i = 0; i < IT; i++)
#pragma unroll
        for (int j = 0; j < 4; j++) acc[i][j] = mfma16(af[i][ki], bfr[j][ki], acc[i][j]);
    __syncthreads();
  }

  // epilogue: C/D layout col=lane&15, row=quad*4+r
#pragma unroll
  for (int j = 0; j < 4; j++) {
    int gn = (int)tile_n + wn * 64 + j * 16 + l16;
    float bv = bias[gn];
#pragma unroll
    for (int i = 0; i < IT; i++) {
      long gm0 = tile_m + wm * (IT * 16) + i * 16 + quad * 4;
      if (mode == 3) {
#pragma unroll
        for (int r = 0; r < 4; r++) {
          long idx = (gm0 + r) * EMBED + gn;
          ((float*)outp)[idx] = acc[i][j][r] + bv + resid[idx];
        }
      } else if (mode == 2) {
        // V^T: lane's 4 values are consecutive l at fixed dh -> one b64 store
        int b = (int)(gm0 >> 11), l = (int)(gm0 & 2047);
        int hh = gn >> 6, dh = gn & 63;
        uint2 pk;
        pk.x = (u32)f2bf(acc[i][j][0] + bv) | ((u32)f2bf(acc[i][j][1] + bv) << 16);
        pk.y = (u32)f2bf(acc[i][j][2] + bv) | ((u32)f2bf(acc[i][j][3] + bv) << 16);
        *(uint2*)((u16*)outp + (long)((b * HEADS + hh) * DH + dh) * LQ + l) = pk;
      } else {
#pragma unroll
        for (int r = 0; r < 4; r++) {
          long gm = gm0 + r;
          float v = acc[i][j][r] + bv;
          if (mode == 0) v *= QSCALE;
          int b = (int)(gm >> 11), l = (int)(gm & 2047);
          int hh = gn >> 6, dh = gn & 63;
          ((u16*)outp)[(long)((b * HEADS + hh) * LQ + l) * DH + dh] = f2bf(v);
        }
      }
    }
  }
}

__global__ __launch_bounds__(256) void qkv_kernel(
    const u16* __restrict__ qb, const u16* __restrict__ kvb,
    const u16* __restrict__ wqb, const u16* __restrict__ wkb, const u16* __restrict__ wvb,
    const float* __restrict__ bq, const float* __restrict__ bk, const float* __restrict__ bv,
    u16* __restrict__ Qh, u16* __restrict__ Kh, u16* __restrict__ Vt) {
  __shared__ u16 As[128 * 64];   // 16 KB
  __shared__ u16 Bs[128 * 64];   // 16 KB
  if (blockIdx.z == 0)      gemm_core<4>(As, Bs, qb,  wqb, bq, nullptr, Qh, 0, blockIdx.x, blockIdx.y);
  else if (blockIdx.z == 1) gemm_core<4>(As, Bs, kvb, wkb, bk, nullptr, Kh, 1, blockIdx.x, blockIdx.y);
  else                      gemm_core<4>(As, Bs, kvb, wvb, bv, nullptr, Vt, 2, blockIdx.x, blockIdx.y);
}

__global__ __launch_bounds__(256) void oproj_kernel(
    const u16* __restrict__ ctx, const u16* __restrict__ wob,
    const float* __restrict__ bo, const float* __restrict__ resid, float* __restrict__ out) {
  __shared__ u16 As[64 * 64];    // 8 KB
  __shared__ u16 Bs[128 * 64];   // 16 KB
  gemm_core<2>(As, Bs, ctx, wob, bo, resid, out, 3, blockIdx.x, blockIdx.y);
}

// ---- flash attention v3: no K/V LDS, no in-loop barriers, K-split waves ----
// K/V per bh is only 512 KB (16 MB total) -> L2/L3-resident; LDS staging was
// pure overhead + barrier coupling (Common-mistake #7). Each wave owns 32
// qrows x HALF the keys (16 of 32 key-tiles) and free-runs: K/V fragments are
// read straight from global into registers, single-buffered -- reloads issue
// right after the consuming MFMAs, so their latency hides under softmax+PV
// (~400 cyc windows) and under 3-waves/SIMD TLP. Block = 4 waves = 2 q-subtiles
// x 2 K-halves (64 qrows); grid 32 qt x 32 bh = 1024 (2x more blocks).
// Since softmax has no max-subtraction, partial O and lsum from the two
// K-halves combine ADDITIVELY: one padded-LDS exchange + single barrier.
// XCD swizzle: each XCD owns 4 consecutive bh -> 2 MB K/V working set < 4 MB L2.
__global__ __launch_bounds__(256, 3) void attn_kernel(
    const u16* __restrict__ Qh, const u16* __restrict__ Kh,
    const u16* __restrict__ Vt, u16* __restrict__ ctx) {
  __shared__ float mrg[2][64][33];  // K-half merge buffer, +1 pad (2-way free)
  __shared__ float mls[2][64];
  const int tid = threadIdx.x;
  const int lane = tid & 63;
  const int wv = tid >> 6;
  const int qsub = wv >> 1;   // which 32-qrow subtile of the block's 64
  const int kh2 = wv & 1;     // which K half (16 tiles each)
  const int l32 = lane & 31, h = lane >> 5;

  // XCD swizzle: flat id round-robins XCDs (id%8); give XCD x bh in [4x,4x+4)
  int i = (int)blockIdx.x;
  int xcd = i & 7, j = i >> 3;
  int bh = (xcd << 2) | (j >> 5);
  int qt = j & 31;  // 64-row q tile

  const long qoff = (long)bh * (LQ * DH) + (long)(qt * 64 + qsub * 32) * DH;
  const long koff = (long)bh * (LQ * DH);
  const long voff = (long)bh * (DH * LQ);

  // Q B-frags direct from global: qrow = l32, d-chunk = ks*16 + 8h + (0..7)
  bf16x8 bq[4];
#pragma unroll
  for (int ks = 0; ks < 4; ks++)
    bq[ks] = *(const bf16x8*)(Qh + qoff + l32 * DH + ks * 16 + h * 8);

  f32x16 z16 = {0.f, 0.f, 0.f, 0.f, 0.f, 0.f, 0.f, 0.f,
                0.f, 0.f, 0.f, 0.f, 0.f, 0.f, 0.f, 0.f};
  f32x16 ot[2];
  ot[0] = z16;
  ot[1] = z16;
  float2 ls2 = {0.f, 0.f};

  bf16x8 kf[8];  // K(t) frags [ks*2+mt]
  bf16x8 vf[8];  // V(t) frags [s*2+mt2]
  const int t0 = kh2 * 16;

  // K frag: rows kt*64 + mt*32 + l32 of [bh][L][64], k-chunk ks*16+8h
  auto load_K = [&](int kt) {
#pragma unroll
    for (int ks = 0; ks < 4; ks++)
#pragma unroll
      for (int mt = 0; mt < 2; mt++)
        kf[ks * 2 + mt] = *(const bf16x8*)(
            Kh + koff + (long)(kt * 64 + mt * 32 + l32) * 64 + ks * 16 + h * 8);
  };
  // V^T frag: rows dh = mt2*32 + l32 of [bh][64][L], key-chunk kt*64+s*16+8h
  auto load_V = [&](int kt) {
#pragma unroll
    for (int s = 0; s < 4; s++)
#pragma unroll
      for (int mt2 = 0; mt2 < 2; mt2++)
        vf[s * 2 + mt2] = *(const bf16x8*)(
            Vt + voff + (long)(mt2 * 32 + l32) * LQ + kt * 64 + s * 16 + h * 8);
  };

  load_K(t0);
  load_V(t0);

  f32x16 st[2];
  uint2 pk[2][4];

  for (int t = 0; t < 16; t++) {
    int kt = t0 + t;

    // S^T = K . Q^T : 64 keys x 32 qrows (consumes kf)
    st[0] = z16;
    st[1] = z16;
    __builtin_amdgcn_s_setprio(1);
#pragma unroll
    for (int ks = 0; ks < 4; ks++) {
#pragma unroll
      for (int mt = 0; mt < 2; mt++) st[mt] = mfma32(kf[ks * 2 + mt], bq[ks], st[mt]);
    }
    __builtin_amdgcn_s_setprio(0);
    if (t + 1 < 16) load_K(kt + 1);  // latency hides under softmax+PV

    // p = 2^s; lane's scores: qrow = l32(+qsub*32), key = mt*32 + 8g + 4h + r
#pragma unroll
    for (int mt = 0; mt < 2; mt++) {
#pragma unroll
      for (int g = 0; g < 4; g++) {
        float p0 = exp2f(st[mt][g * 4 + 0]);
        float p1 = exp2f(st[mt][g * 4 + 1]);
        float p2 = exp2f(st[mt][g * 4 + 2]);
        float p3 = exp2f(st[mt][g * 4 + 3]);
        ls2.x += p0 + p2;
        ls2.y += p1 + p3;
        pk[mt][g].x = packbf(p0, p1);
        pk[mt][g].y = packbf(p2, p3);
      }
    }

    // O^T += V^T . P at x16 rate: kstep s covers keys 16s..16s+15. B-frag
    // assembled from own packed words + cross-half partner's via permlane32.
#pragma unroll
    for (int s = 0; s < 4; s++) {
      uint2 wa = pk[s >> 1][(s & 1) * 2];
      uint2 wb = pk[s >> 1][(s & 1) * 2 + 1];
      u32 a0 = wa.x, b0 = wb.x, a1 = wa.y, b1 = wb.y;
      pl32(a0, b0);
      pl32(a1, b1);
      union { u32 u[4]; bf16x8 v; } bp;
      bp.u[0] = a0;
      bp.u[1] = a1;
      bp.u[2] = b0;
      bp.u[3] = b1;
      __builtin_amdgcn_s_setprio(1);
#pragma unroll
      for (int mt2 = 0; mt2 < 2; mt2++) ot[mt2] = mfma32(vf[s * 2 + mt2], bp.v, ot[mt2]);
      __builtin_amdgcn_s_setprio(0);
    }
    if (t + 1 < 16) load_V(kt + 1);  // latency hides under next S + softmax
  }

  // ---- merge the two K-halves (additive: no max-tracking) ----
  float lsum = ls2.x + ls2.y;
  if (kh2 == 1) {
#pragma unroll
    for (int mt = 0; mt < 2; mt++)
#pragma unroll
      for (int e = 0; e < 16; e++) mrg[qsub][lane][mt * 16 + e] = ot[mt][e];
    mls[qsub][lane] = lsum;
  }
  __syncthreads();
  if (kh2 == 0) {
    lsum += mls[qsub][lane];
    lsum += __shfl_xor(lsum, 32);  // combine the two lane-halves (same qrow)
    float inv = 1.0f / lsum;
    const int b = bh >> 4, head = bh & 15;
    int qrow = qt * 64 + qsub * 32 + l32;
    long base = (long)(b * LQ + qrow) * EMBED + head * DH;
#pragma unroll
    for (int mt = 0; mt < 2; mt++) {
#pragma unroll
      for (int g = 0; g < 4; g++) {
        float o0 = (ot[mt][g * 4 + 0] + mrg[qsub][lane][mt * 16 + g * 4 + 0]) * inv;
        float o1 = (ot[mt][g * 4 + 1] + mrg[qsub][lane][mt * 16 + g * 4 + 1]) * inv;
        float o2 = (ot[mt][g * 4 + 2] + mrg[qsub][lane][mt * 16 + g * 4 + 2]) * inv;
        float o3 = (ot[mt][g * 4 + 3] + mrg[qsub][lane][mt * 16 + g * 4 + 3]) * inv;
        uint2 pkk;
        pkk.x = (u32)f2bf(o0) | ((u32)f2bf(o1) << 16);
        pkk.y = (u32)f2bf(o2) | ((u32)f2bf(o3) << 16);
        *(uint2*)(ctx + base + mt * 32 + g * 8 + 4 * h) = pkk;
      }
    }
  }
}

// ---------------- LayerNorm in place on d_out ----------------
__global__ __launch_bounds__(256) void ln_kernel(
    float* __restrict__ x, const float* __restrict__ gamma, const float* __restrict__ beta) {
  __shared__ float red[8];
  const int tid = threadIdx.x;
  const long row = blockIdx.x;
  float4 v = *(const float4*)(x + row * EMBED + tid * 4);
  float s = v.x + v.y + v.z + v.w;
  float sq = v.x * v.x + v.y * v.y + v.z * v.z + v.w * v.w;
#pragma unroll
  for (int off = 1; off < 64; off <<= 1) {
    s += __shfl_xor(s, off);
    sq += __shfl_xor(sq, off);
  }
  if ((tid & 63) == 0) {
    red[(tid >> 6) * 2] = s;
    red[(tid >> 6) * 2 + 1] = sq;
  }
  __syncthreads();
  s = red[0] + red[2] + red[4] + red[6];
  sq = red[1] + red[3] + red[5] + red[7];
  float mu = s * (1.f / EMBED);
  float var = sq * (1.f / EMBED) - mu * mu;
  float rstd = rsqrtf(var + 1e-5f);
  float4 g = *(const float4*)(gamma + tid * 4);
  float4 bt = *(const float4*)(beta + tid * 4);
  float4 ov;
  ov.x = (v.x - mu) * rstd * g.x + bt.x;
  ov.y = (v.y - mu) * rstd * g.y + bt.y;
  ov.z = (v.z - mu) * rstd * g.z + bt.z;
  ov.w = (v.w - mu) * rstd * g.w + bt.w;
  *(float4*)(x + row * EMBED + tid * 4) = ov;
}

extern "C" void kernel_launch(void* const* d_in, const int* in_sizes, int n_in,
                              void* d_out, int out_size, void* d_ws, size_t ws_size,
                              hipStream_t stream) {
  const float* q     = (const float*)d_in[0];
  const float* kv    = (const float*)d_in[1];
  // d_in[2] = prompt_size (0, unused)
  const float* Wq    = (const float*)d_in[3];
  const float* bq    = (const float*)d_in[4];
  const float* Wk    = (const float*)d_in[5];
  const float* bk    = (const float*)d_in[6];
  const float* Wv    = (const float*)d_in[7];
  const float* bv    = (const float*)d_in[8];
  const float* Wo    = (const float*)d_in[9];
  const float* bo    = (const float*)d_in[10];
  const float* gamma = (const float*)d_in[11];
  const float* beta  = (const float*)d_in[12];

  char* ws = (char*)d_ws;
  u16* qb  = (u16*)(ws + (0l  << 20));  // 8 MB
  u16* kvb = (u16*)(ws + (8l  << 20));  // 8 MB
  u16* wqb = (u16*)(ws + (16l << 20));  // 2 MB
  u16* wkb = (u16*)(ws + (18l << 20));
  u16* wvb = (u16*)(ws + (20l << 20));
  u16* wob = (u16*)(ws + (22l << 20));
  u16* Qh  = (u16*)(ws + (24l << 20));  // 8 MB [bh][L][64] (pre-scaled by QSCALE)
  u16* Kh  = (u16*)(ws + (32l << 20));  // 8 MB [bh][L][64]
  u16* Vt  = (u16*)(ws + (40l << 20));  // 8 MB [bh][64][L]
  u16* ctx = (u16*)(ws + (48l << 20));  // 8 MB [B][L][E]   (total 56 MB)
  float* out = (float*)d_out;

  cast_kernel<<<6144, 256, 0, stream>>>(q, kv, Wq, Wk, Wv, Wo, qb, kvb, wqb, wkb, wvb, wob);
  qkv_kernel<<<dim3(32, 8, 3), 256, 0, stream>>>(qb, kvb, wqb, wkb, wvb, bq, bk, bv, Qh, Kh, Vt);
  attn_kernel<<<1024, 256, 0, stream>>>(Qh, Kh, Vt, ctx);
  oproj_kernel<<<dim3(64, 8), 256, 0, stream>>>(ctx, wob, bo, q, out);
  ln_kernel<<<4096, 256, 0, stream>>>(out, gamma, beta);
}

// Round 3
// 222.372 us; speedup vs baseline: 1.5468x; 1.5468x over previous
//
#include <hip/hip_runtime.h>

typedef unsigned short u16;
typedef unsigned int u32;
typedef __attribute__((ext_vector_type(8))) __bf16 bf16x8;
typedef __attribute__((ext_vector_type(4))) float f32x4;
typedef __attribute__((ext_vector_type(16))) float f32x16;

#define EMBED 1024
#define NB 2
#define LQ 2048
#define HEADS 16
#define DH 64
// log2(e) / sqrt(64) -- folded into Q at projection time
#define QSCALE 0.18033688011112042f

__device__ __forceinline__ u16 f2bf(float f) {
  u32 u = __float_as_uint(f);
  u32 r = (u + 0x7FFFu + ((u >> 16) & 1u)) >> 16;  // RNE
  return (u16)r;
}

__device__ __forceinline__ void glds16(const void* g, void* l) {
  __builtin_amdgcn_global_load_lds((const __attribute__((address_space(1))) void*)g,
                                   (__attribute__((address_space(3))) void*)l, 16, 0, 0);
}

__device__ __forceinline__ f32x4 mfma16(bf16x8 a, bf16x8 b, f32x4 c) {
  return __builtin_amdgcn_mfma_f32_16x16x32_bf16(a, b, c, 0, 0, 0);
}
__device__ __forceinline__ f32x16 mfma32(bf16x8 a, bf16x8 b, f32x16 c) {
  return __builtin_amdgcn_mfma_f32_32x32x16_bf16(a, b, c, 0, 0, 0);
}

// v_permlane32_swap_b32: a[l>=32] <-> b[l-32]. Register-only exchange.
__device__ __forceinline__ void pl32(u32& a, u32& b) {
  asm("v_permlane32_swap_b32 %0, %1" : "+v"(a), "+v"(b));
}

// pack two floats to bf16 pair (truncating): low = a, high = b
__device__ __forceinline__ u32 packbf(float a, float b) {
  return __builtin_amdgcn_perm(__float_as_uint(b), __float_as_uint(a), 0x07060302u);
}

// ---------------- cast fp32 -> bf16 for activations + weights ----------------
__global__ __launch_bounds__(256) void cast_kernel(
    const float* __restrict__ q, const float* __restrict__ kv,
    const float* __restrict__ wq, const float* __restrict__ wk,
    const float* __restrict__ wv, const float* __restrict__ wo,
    u16* __restrict__ qb, u16* __restrict__ kvb, u16* __restrict__ wqb,
    u16* __restrict__ wkb, u16* __restrict__ wvb, u16* __restrict__ wob) {
  int bid = blockIdx.x;
  const float* src;
  u16* dst;
  long base;
  if (bid < 2048) {
    src = q; dst = qb; base = (long)bid * 2048;
  } else if (bid < 4096) {
    src = kv; dst = kvb; base = (long)(bid - 2048) * 2048;
  } else {
    int wsel = (bid - 4096) >> 9;
    int wb = (bid - 4096) & 511;
    if (wsel == 0) { src = wq; dst = wqb; }
    else if (wsel == 1) { src = wk; dst = wkb; }
    else if (wsel == 2) { src = wv; dst = wvb; }
    else { src = wo; dst = wob; }
    base = (long)wb * 2048;
  }
  long e = base + (long)threadIdx.x * 8;
  float4 f0 = *(const float4*)(src + e);
  float4 f1 = *(const float4*)(src + e + 4);
  uint4 o;
  o.x = (u32)f2bf(f0.x) | ((u32)f2bf(f0.y) << 16);
  o.y = (u32)f2bf(f0.z) | ((u32)f2bf(f0.w) << 16);
  o.z = (u32)f2bf(f1.x) | ((u32)f2bf(f1.y) << 16);
  o.w = (u32)f2bf(f1.z) | ((u32)f2bf(f1.w) << 16);
  *(uint4*)(dst + e) = o;
}

// ------------- GEMM: C = A @ W^T (+bias, mode-specific epilogue), BK=64 ------
// mode 0: Q -> [bh][L][64], scaled by QSCALE; 1: K -> same layout unscaled;
// mode 2: V -> [bh][64][L] (transposed, b64-packed stores);
// mode 3: fp32 out = acc + bias + resid (pre-LN x).
template <int IT>
__device__ __forceinline__ void gemm_core(
    u16* As, u16* Bs, const u16* __restrict__ A, const u16* __restrict__ W,
    const float* __restrict__ bias, const float* __restrict__ resid,
    void* __restrict__ outp, int mode, int bx, int by) {
  const int K = EMBED;
  const int TM = IT * 32;
  const int tid = threadIdx.x;
  const int lane = tid & 63;
  const int wv = tid >> 6;
  const int wm = wv >> 1, wn = wv & 1;
  const int l16 = lane & 15, quad = lane >> 4;
  const long tile_m = (long)bx * TM;
  const long tile_n = (long)by * 128;

  f32x4 z4 = {0.f, 0.f, 0.f, 0.f};
  f32x4 acc[IT][4];
#pragma unroll
  for (int i = 0; i < IT; i++)
#pragma unroll
    for (int j = 0; j < 4; j++) acc[i][j] = z4;

  for (int k0 = 0; k0 < K; k0 += 64) {
    // stage A: TM rows x 8 chunks(16B), XOR swizzle cc ^ (row&7)
#pragma unroll
    for (int it = 0; it < TM / 32; it++) {
      int lin = it * 256 + tid;
      int row = lin >> 3, cc = lin & 7;
      glds16(A + (tile_m + row) * K + k0 + ((cc ^ (row & 7)) << 3), As + lin * 8);
    }
#pragma unroll
    for (int it = 0; it < 4; it++) {
      int lin = it * 256 + tid;
      int row = lin >> 3, cc = lin & 7;
      glds16(W + (tile_n + row) * K + k0 + ((cc ^ (row & 7)) << 3), Bs + lin * 8);
    }
    __syncthreads();
    bf16x8 af[IT][2], bfr[4][2];
#pragma unroll
    for (int i = 0; i < IT; i++) {
      int row = wm * (IT * 16) + i * 16 + l16;
#pragma unroll
      for (int ki = 0; ki < 2; ki++)
        af[i][ki] = *(const bf16x8*)(As + row * 64 + (((ki * 4 + quad) ^ (row & 7)) << 3));
    }
#pragma unroll
    for (int j = 0; j < 4; j++) {
      int row = wn * 64 + j * 16 + l16;
#pragma unroll
      for (int ki = 0; ki < 2; ki++)
        bfr[j][ki] = *(const bf16x8*)(Bs + row * 64 + (((ki * 4 + quad) ^ (row & 7)) << 3));
    }
#pragma unroll
    for (int ki = 0; ki < 2; ki++)
#pragma unroll
      for (int i = 0; i < IT; i++)
#pragma unroll
        for (int j = 0; j < 4; j++) acc[i][j] = mfma16(af[i][ki], bfr[j][ki], acc[i][j]);
    __syncthreads();
  }

  // epilogue: C/D layout col=lane&15, row=quad*4+r
#pragma unroll
  for (int j = 0; j < 4; j++) {
    int gn = (int)tile_n + wn * 64 + j * 16 + l16;
    float bv = bias[gn];
#pragma unroll
    for (int i = 0; i < IT; i++) {
      long gm0 = tile_m + wm * (IT * 16) + i * 16 + quad * 4;
      if (mode == 3) {
#pragma unroll
        for (int r = 0; r < 4; r++) {
          long idx = (gm0 + r) * EMBED + gn;
          ((float*)outp)[idx] = acc[i][j][r] + bv + resid[idx];
        }
      } else if (mode == 2) {
        // V^T: lane's 4 values are consecutive l at fixed dh -> one b64 store
        int b = (int)(gm0 >> 11), l = (int)(gm0 & 2047);
        int hh = gn >> 6, dh = gn & 63;
        uint2 pk;
        pk.x = (u32)f2bf(acc[i][j][0] + bv) | ((u32)f2bf(acc[i][j][1] + bv) << 16);
        pk.y = (u32)f2bf(acc[i][j][2] + bv) | ((u32)f2bf(acc[i][j][3] + bv) << 16);
        *(uint2*)((u16*)outp + (long)((b * HEADS + hh) * DH + dh) * LQ + l) = pk;
      } else {
#pragma unroll
        for (int r = 0; r < 4; r++) {
          long gm = gm0 + r;
          float v = acc[i][j][r] + bv;
          if (mode == 0) v *= QSCALE;
          int b = (int)(gm >> 11), l = (int)(gm & 2047);
          int hh = gn >> 6, dh = gn & 63;
          ((u16*)outp)[(long)((b * HEADS + hh) * LQ + l) * DH + dh] = f2bf(v);
        }
      }
    }
  }
}

__global__ __launch_bounds__(256) void qkv_kernel(
    const u16* __restrict__ qb, const u16* __restrict__ kvb,
    const u16* __restrict__ wqb, const u16* __restrict__ wkb, const u16* __restrict__ wvb,
    const float* __restrict__ bq, const float* __restrict__ bk, const float* __restrict__ bv,
    u16* __restrict__ Qh, u16* __restrict__ Kh, u16* __restrict__ Vt) {
  __shared__ u16 As[128 * 64];   // 16 KB
  __shared__ u16 Bs[128 * 64];   // 16 KB
  if (blockIdx.z == 0)      gemm_core<4>(As, Bs, qb,  wqb, bq, nullptr, Qh, 0, blockIdx.x, blockIdx.y);
  else if (blockIdx.z == 1) gemm_core<4>(As, Bs, kvb, wkb, bk, nullptr, Kh, 1, blockIdx.x, blockIdx.y);
  else                      gemm_core<4>(As, Bs, kvb, wvb, bv, nullptr, Vt, 2, blockIdx.x, blockIdx.y);
}

__global__ __launch_bounds__(256) void oproj_kernel(
    const u16* __restrict__ ctx, const u16* __restrict__ wob,
    const float* __restrict__ bo, const float* __restrict__ resid, float* __restrict__ out) {
  __shared__ u16 As[64 * 64];    // 8 KB
  __shared__ u16 Bs[128 * 64];   // 16 KB
  gemm_core<2>(As, Bs, ctx, wob, bo, resid, out, 3, blockIdx.x, blockIdx.y);
}

// ---- flash attention: LDS-staged ring-3, pipelined S, const ring slots -----
// R1 structure (verified 65.9us): block = 4 waves x 32 qrows; 64-key tiles,
// K/V ring-3 in LDS, 1 barrier/iter; softmax+PV of tile t-1 overlaps S of
// tile t. This revision attacks the measured VALU bound (52% busy):
//  (a) exp2f -> raw v_exp_f32 (__builtin_amdgcn_exp2f): libm's precise path
//      was ~8 VALU insts per value x 32 values/iter.
//  (b) ring indices are COMPILE-TIME (period-3 unroll, AITER(kt,P,C,N)
//      macro): every ds_read address folds to hoisted invariant vaddr +
//      16-bit immediate offset -- zero per-iter LDS address arithmetic.
// PV at full x16 rate via permlane32-assembled B-frags (R1).
__global__ __launch_bounds__(256, 2) void attn_kernel(
    const u16* __restrict__ Qh, const u16* __restrict__ Kh,
    const u16* __restrict__ Vt, u16* __restrict__ ctx) {
  __shared__ u16 Qs[128 * 64];        // 16 KB
  __shared__ u16 KVs[3][2][64 * 64];  // 48 KB: ring[3] x [K/V] x 64x64
  const int tid = threadIdx.x;
  const int lane = tid & 63;
  const int wv = tid >> 6;             // wave owns qrows wv*32 .. wv*32+31
  const int l32 = lane & 31, h = lane >> 5;
  const int qt = blockIdx.x, bh = blockIdx.y;
  const long qoff = (long)bh * (LQ * DH) + (long)qt * (128 * DH);
  const long koff = (long)bh * (LQ * DH);
  const long voff = (long)bh * (DH * LQ);
  const int qbase = wv * 32;

// stage K/V tile t into ring slot N (N is a literal -> const LDS dest)
#define STAGE_KV(t, N)                                                          \
  do {                                                                          \
    _Pragma("unroll") for (int it = 0; it < 2; it++) {                          \
      int lin = it * 256 + tid;                                                 \
      int row = lin >> 3, cc = lin & 7;                                         \
      glds16(Kh + koff + (long)((t) * 64 + row) * 64 + ((cc ^ (row & 7)) << 3), \
             &KVs[N][0][0] + lin * 8);                                          \
      glds16(Vt + voff + (long)row * LQ + (t) * 64 + ((cc ^ (row & 7)) << 3),   \
             &KVs[N][1][0] + lin * 8);                                          \
    }                                                                           \
  } while (0)

  // stage Q tile 128x64 + first TWO K/V tiles (ring 0,1)
#pragma unroll
  for (int it = 0; it < 4; it++) {
    int lin = it * 256 + tid;
    int row = lin >> 3, cc = lin & 7;
    glds16(Qh + qoff + row * 64 + ((cc ^ (row & 7)) << 3), Qs + lin * 8);
  }
  STAGE_KV(0, 0);
  STAGE_KV(1, 1);
  __syncthreads();

  // hoisted Q B-frags: n = qbase+l32, kstep ks: d = ks*16 + 8h + (0..7)
  bf16x8 bq[4];
  {
    int row = qbase + l32;
#pragma unroll
    for (int ks = 0; ks < 4; ks++)
      bq[ks] = *(const bf16x8*)(Qs + row * 64 + (((ks * 2 + h) ^ (row & 7)) << 3));
  }

  f32x16 z16 = {0.f, 0.f, 0.f, 0.f, 0.f, 0.f, 0.f, 0.f,
                0.f, 0.f, 0.f, 0.f, 0.f, 0.f, 0.f, 0.f};
  f32x16 ot[2];
  ot[0] = z16;
  ot[1] = z16;
  f32x16 st[2];
  uint2 pk[2][4];
  float2 ls2 = {0.f, 0.f};

// S^T = K . Q^T : 64 keys (2 m-tiles) x 32 qrows from ring slot C (literal)
#define DO_S(C)                                                                  \
  do {                                                                           \
    st[0] = z16;                                                                 \
    st[1] = z16;                                                                 \
    __builtin_amdgcn_s_setprio(1);                                               \
    _Pragma("unroll") for (int ks = 0; ks < 4; ks++) {                           \
      _Pragma("unroll") for (int mt = 0; mt < 2; mt++) {                         \
        int row = mt * 32 + l32;                                                 \
        bf16x8 ak = *(const bf16x8*)(&KVs[C][0][0] + row * 64 +                  \
                                     (((ks * 2 + h) ^ (row & 7)) << 3));         \
        st[mt] = mfma32(ak, bq[ks], st[mt]);                                     \
      }                                                                          \
    }                                                                            \
    __builtin_amdgcn_s_setprio(0);                                               \
  } while (0)

// p = 2^s via raw v_exp_f32; lane: qrow = qbase+l32, key = mt*32 + 8g + 4h + r
#define DO_SM()                                                                  \
  do {                                                                           \
    _Pragma("unroll") for (int mt = 0; mt < 2; mt++) {                           \
      _Pragma("unroll") for (int g = 0; g < 4; g++) {                            \
        float p0 = __builtin_amdgcn_exp2f(st[mt][g * 4 + 0]);                    \
        float p1 = __builtin_amdgcn_exp2f(st[mt][g * 4 + 1]);                    \
        float p2 = __builtin_amdgcn_exp2f(st[mt][g * 4 + 2]);                    \
        float p3 = __builtin_amdgcn_exp2f(st[mt][g * 4 + 3]);                    \
        ls2.x += p0 + p2;                                                        \
        ls2.y += p1 + p3;                                                        \
        pk[mt][g].x = packbf(p0, p1);                                            \
        pk[mt][g].y = packbf(p2, p3);                                            \
      }                                                                          \
    }                                                                            \
  } while (0)

// O^T += V^T . P at x16 rate from ring slot P (literal). B-frag words (keys
// 16s+8h+{0..7}) from own pk + cross-half partner via permlane32_swap.
#define DO_PV(P)                                                                 \
  do {                                                                           \
    _Pragma("unroll") for (int s = 0; s < 4; s++) {                              \
      uint2 wa = pk[s >> 1][(s & 1) * 2];                                        \
      uint2 wb = pk[s >> 1][(s & 1) * 2 + 1];                                    \
      u32 a0 = wa.x, b0 = wb.x, a1 = wa.y, b1 = wb.y;                            \
      pl32(a0, b0);                                                              \
      pl32(a1, b1);                                                              \
      union { u32 u[4]; bf16x8 v; } bp;                                          \
      bp.u[0] = a0;                                                              \
      bp.u[1] = a1;                                                              \
      bp.u[2] = b0;                                                              \
      bp.u[3] = b1;                                                              \
      __builtin_amdgcn_s_setprio(1);                                             \
      _Pragma("unroll") for (int mt2 = 0; mt2 < 2; mt2++) {                      \
        int row = mt2 * 32 + l32;                                                \
        bf16x8 av = *(const bf16x8*)(&KVs[P][1][0] + row * 64 +                  \
                                     ((((s << 1) + h) ^ (row & 7)) << 3));       \
        ot[mt2] = mfma32(av, bp.v, ot[mt2]);                                     \
      }                                                                          \
      __builtin_amdgcn_s_setprio(0);                                             \
    }                                                                            \
  } while (0)

// one pipeline iteration: stage tile kt+1 -> slot N, softmax S(kt-1),
// S of tile kt from slot C, PV of tile kt-1 from slot P. Slot of tile t = t%3.
#define AITER(kt, P, C, N)                                                       \
  do {                                                                           \
    if ((kt) + 1 < 32) STAGE_KV((kt) + 1, N);                                    \
    DO_SM();                                                                     \
    DO_S(C);                                                                     \
    DO_PV(P);                                                                    \
    __syncthreads();                                                             \
  } while (0)

  DO_S(0);  // prologue: scores of tile 0 (softmax'd in iter 1)

  AITER(1, 0, 1, 2);
  for (int k0 = 2; k0 < 32; k0 += 3) {  // k0 = 2,5,...,29 -> kt = 2..31
    AITER(k0, 1, 2, 0);
    AITER(k0 + 1, 2, 0, 1);
    AITER(k0 + 2, 0, 1, 2);
  }
  DO_SM();    // softmax of S(31)
  DO_PV(1);   // V(31) resides in slot 31%3 = 1

#undef STAGE_KV
#undef DO_S
#undef DO_SM
#undef DO_PV
#undef AITER

  // lsum: fold float2 + combine the two lane-halves holding the same qrow
  float lsum = ls2.x + ls2.y;
  lsum += __shfl_xor(lsum, 32);
  float inv = 1.0f / lsum;

  // epilogue: lane holds qrow = qt*128 + qbase + l32, d = mt*32 + g*8 + 4h + r
  const int b = bh >> 4, head = bh & 15;
  int qrow = qt * 128 + qbase + l32;
  long base = (long)(b * LQ + qrow) * EMBED + head * DH;
#pragma unroll
  for (int mt = 0; mt < 2; mt++) {
#pragma unroll
    for (int g = 0; g < 4; g++) {
      uint2 pkk;
      pkk.x = (u32)f2bf(ot[mt][g * 4 + 0] * inv) | ((u32)f2bf(ot[mt][g * 4 + 1] * inv) << 16);
      pkk.y = (u32)f2bf(ot[mt][g * 4 + 2] * inv) | ((u32)f2bf(ot[mt][g * 4 + 3] * inv) << 16);
      *(uint2*)(ctx + base + mt * 32 + g * 8 + 4 * h) = pkk;
    }
  }
}

// ---------------- LayerNorm in place on d_out ----------------
__global__ __launch_bounds__(256) void ln_kernel(
    float* __restrict__ x, const float* __restrict__ gamma, const float* __restrict__ beta) {
  __shared__ float red[8];
  const int tid = threadIdx.x;
  const long row = blockIdx.x;
  float4 v = *(const float4*)(x + row * EMBED + tid * 4);
  float s = v.x + v.y + v.z + v.w;
  float sq = v.x * v.x + v.y * v.y + v.z * v.z + v.w * v.w;
#pragma unroll
  for (int off = 1; off < 64; off <<= 1) {
    s += __shfl_xor(s, off);
    sq += __shfl_xor(sq, off);
  }
  if ((tid & 63) == 0) {
    red[(tid >> 6) * 2] = s;
    red[(tid >> 6) * 2 + 1] = sq;
  }
  __syncthreads();
  s = red[0] + red[2] + red[4] + red[6];
  sq = red[1] + red[3] + red[5] + red[7];
  float mu = s * (1.f / EMBED);
  float var = sq * (1.f / EMBED) - mu * mu;
  float rstd = rsqrtf(var + 1e-5f);
  float4 g = *(const float4*)(gamma + tid * 4);
  float4 bt = *(const float4*)(beta + tid * 4);
  float4 ov;
  ov.x = (v.x - mu) * rstd * g.x + bt.x;
  ov.y = (v.y - mu) * rstd * g.y + bt.y;
  ov.z = (v.z - mu) * rstd * g.z + bt.z;
  ov.w = (v.w - mu) * rstd * g.w + bt.w;
  *(float4*)(x + row * EMBED + tid * 4) = ov;
}

extern "C" void kernel_launch(void* const* d_in, const int* in_sizes, int n_in,
                              void* d_out, int out_size, void* d_ws, size_t ws_size,
                              hipStream_t stream) {
  const float* q     = (const float*)d_in[0];
  const float* kv    = (const float*)d_in[1];
  // d_in[2] = prompt_size (0, unused)
  const float* Wq    = (const float*)d_in[3];
  const float* bq    = (const float*)d_in[4];
  const float* Wk    = (const float*)d_in[5];
  const float* bk    = (const float*)d_in[6];
  const float* Wv    = (const float*)d_in[7];
  const float* bv    = (const float*)d_in[8];
  const float* Wo    = (const float*)d_in[9];
  const float* bo    = (const float*)d_in[10];
  const float* gamma = (const float*)d_in[11];
  const float* beta  = (const float*)d_in[12];

  char* ws = (char*)d_ws;
  u16* qb  = (u16*)(ws + (0l  << 20));  // 8 MB
  u16* kvb = (u16*)(ws + (8l  << 20));  // 8 MB
  u16* wqb = (u16*)(ws + (16l << 20));  // 2 MB
  u16* wkb = (u16*)(ws + (18l << 20));
  u16* wvb = (u16*)(ws + (20l << 20));
  u16* wob = (u16*)(ws + (22l << 20));
  u16* Qh  = (u16*)(ws + (24l << 20));  // 8 MB [bh][L][64] (pre-scaled by QSCALE)
  u16* Kh  = (u16*)(ws + (32l << 20));  // 8 MB [bh][L][64]
  u16* Vt  = (u16*)(ws + (40l << 20));  // 8 MB [bh][64][L]
  u16* ctx = (u16*)(ws + (48l << 20));  // 8 MB [B][L][E]   (total 56 MB)
  float* out = (float*)d_out;

  cast_kernel<<<6144, 256, 0, stream>>>(q, kv, Wq, Wk, Wv, Wo, qb, kvb, wqb, wkb, wvb, wob);
  qkv_kernel<<<dim3(32, 8, 3), 256, 0, stream>>>(qb, kvb, wqb, wkb, wvb, bq, bk, bv, Qh, Kh, Vt);
  attn_kernel<<<dim3(16, 32), 256, 0, stream>>>(Qh, Kh, Vt, ctx);
  oproj_kernel<<<dim3(64, 8), 256, 0, stream>>>(ctx, wob, bo, q, out);
  ln_kernel<<<4096, 256, 0, stream>>>(out, gamma, beta);
}